// Round 4
// baseline (3144.393 us; speedup 1.0000x reference)
//
#include <hip/hip_runtime.h>
#include <hip/hip_bf16.h>

// LTC, round 4: two-kernel split.
//   Kernel A (ltc_sensory): w_num_s/w_den_s for all (b,t) -> d_ws (134 MB).
//     Grid (B, T/8) x 512 thr. Wave w owns sensory i in [16w,16w+16).
//     Massive parallelism (262k waves), no recurrence.
//   Kernel B (ltc_scan): sequential T-scan, recurrent synapses only.
//     Grid B x 512 thr (8 waves). Wave w owns i in [8w,8w+8).
//     Sensory sums prefetched as float2 per t.
// Both: sigmoid s=1/(1+exp2(a*v+c)); 4-way batched rcp (1 v_rcp / 4 terms,
// exact); 4 INDEPENDENT accumulator chains (round-3 lesson: single-chain
// accumulation serializes); erev sign folded into swe, den weight via free
// abs() fma modifier.
// Fallback: round-1 fused kernel if ws_size < 134 MB.

#define NB 512
#define NT 512
#define NI 128
#define NU 64
#define NO 15
#define L2E 1.44269504088896340736f

typedef float v2f __attribute__((ext_vector_type(2)));

__device__ __forceinline__ float bcastf(float v, int lane) {
  return __int_as_float(__builtin_amdgcn_readlane(__float_as_int(v), lane));
}

__device__ __forceinline__ float wsum64(float x) {
#pragma unroll
  for (int m = 32; m >= 1; m >>= 1) x += __shfl_xor(x, m, 64);
  return x;
}

__device__ __forceinline__ float softplus_f(float x) {
  return log1pf(expf(x));
}

// 4 sigmoids s_i = 1/(1+exp2(z_i)) with ONE v_rcp via product tree (exact).
__device__ __forceinline__ void sig4(float z0, float z1, float z2, float z3,
                                     float& s0, float& s1, float& s2, float& s3) {
  const float e0 = __builtin_amdgcn_exp2f(z0);
  const float e1 = __builtin_amdgcn_exp2f(z1);
  const float e2 = __builtin_amdgcn_exp2f(z2);
  const float e3 = __builtin_amdgcn_exp2f(z3);
  const float A = 1.0f + e0, B = 1.0f + e1, C = 1.0f + e2, D = 1.0f + e3;
  const float pAB = A * B, pCD = C * D;
  const float r = __builtin_amdgcn_rcpf(pAB * pCD);
  const float rAB = r * pCD, rCD = r * pAB;
  s0 = rAB * B; s1 = rAB * A; s2 = rCD * D; s3 = rCD * C;
}

// ---------------- Kernel A: sensory precompute ----------------
__global__ __launch_bounds__(512, 4) void ltc_sensory(
    const float* __restrict__ x,
    const float* __restrict__ input_w, const float* __restrict__ input_b,
    const float* __restrict__ sensory_w, const float* __restrict__ sensory_mu,
    const float* __restrict__ sensory_sigma, const float* __restrict__ sensory_erev,
    v2f* __restrict__ sens)
{
  const int b    = blockIdx.x;
  const int tc   = blockIdx.y;          // chunk of 8 timesteps
  const int tid  = threadIdx.x;
  const int wv   = tid >> 6;            // 0..7, owns i in [16wv,16wv+16)
  const int lane = tid & 63;            // unit j

  __shared__ v2f part[8][8][NU];        // [t][wave][lane]

  float sa[16], sc[16], swe[16];
#pragma unroll
  for (int k = 0; k < 16; ++k) {
    const int idx = (16 * wv + k) * NU + lane;
    const float ss = sensory_sigma[idx];
    const float sm = sensory_mu[idx];
    const float sw = softplus_f(sensory_w[idx]);
    const float ev = sensory_erev[idx];
    sa[k]  = -L2E * ss;
    sc[k]  =  L2E * ss * sm;
    swe[k] = sw * ev;                   // |swe| = softplus(w) since |erev|=1
  }

  const int ii = 16 * wv + (lane & 15);
  const float iw = input_w[ii];
  const float ib = input_b[ii];
  const float* xp = x + ((size_t)b * NT + (size_t)tc * 8) * NI + ii;
  float xv = xp[0];

#pragma unroll
  for (int t = 0; t < 8; ++t) {
    const float xn = (t < 7) ? xp[(t + 1) * NI] : 0.0f;
    const float inp = fmaf(xv, iw, ib);
    float n0=0.f,n1=0.f,n2=0.f,n3=0.f, d0=0.f,d1=0.f,d2=0.f,d3=0.f;
#pragma unroll
    for (int k = 0; k < 16; k += 4) {
      // clamp keeps 4-term product finite (|z| can reach ~70)
      const float z0 = fminf(fmaxf(fmaf(sa[k+0], bcastf(inp, k+0), sc[k+0]), -30.f), 30.f);
      const float z1 = fminf(fmaxf(fmaf(sa[k+1], bcastf(inp, k+1), sc[k+1]), -30.f), 30.f);
      const float z2 = fminf(fmaxf(fmaf(sa[k+2], bcastf(inp, k+2), sc[k+2]), -30.f), 30.f);
      const float z3 = fminf(fmaxf(fmaf(sa[k+3], bcastf(inp, k+3), sc[k+3]), -30.f), 30.f);
      float s0, s1, s2, s3;
      sig4(z0, z1, z2, z3, s0, s1, s2, s3);
      n0 = fmaf(swe[k+0], s0, n0);  d0 = fmaf(fabsf(swe[k+0]), s0, d0);
      n1 = fmaf(swe[k+1], s1, n1);  d1 = fmaf(fabsf(swe[k+1]), s1, d1);
      n2 = fmaf(swe[k+2], s2, n2);  d2 = fmaf(fabsf(swe[k+2]), s2, d2);
      n3 = fmaf(swe[k+3], s3, n3);  d3 = fmaf(fabsf(swe[k+3]), s3, d3);
    }
    part[t][wv][lane] = (v2f){(n0 + n1) + (n2 + n3), (d0 + d1) + (d2 + d3)};
    xv = xn;
  }
  __syncthreads();
  // wave wv reduces timestep t=wv across the 8 wave-partials
  v2f s = part[wv][0][lane];
#pragma unroll
  for (int p = 1; p < 8; ++p) s += part[wv][p][lane];
  sens[((size_t)b * NT + (size_t)tc * 8 + wv) * NU + lane] = s;
}

// ---------------- Kernel B: sequential scan ----------------
__global__ __launch_bounds__(512, 4) void ltc_scan(
    const v2f* __restrict__ sens,
    const float* __restrict__ w_, const float* __restrict__ mu_,
    const float* __restrict__ sigma_, const float* __restrict__ erev_,
    const float* __restrict__ gleak, const float* __restrict__ vleak,
    const float* __restrict__ cm,
    const float* __restrict__ output_w, const float* __restrict__ output_b,
    const float* __restrict__ ln_w, const float* __restrict__ ln_b,
    const float* __restrict__ fc_w, const float* __restrict__ fc_b,
    float* __restrict__ out)
{
  const int b    = blockIdx.x;
  const int tid  = threadIdx.x;
  const int wv   = tid >> 6;            // 0..7, owns i in [8wv,8wv+8)
  const int lane = tid & 63;            // unit j

  __shared__ v2f xbuf[4][8][NU];        // [unfold][wave][lane]

  float ra[8], rc[8], rwe[8];
#pragma unroll
  for (int k = 0; k < 8; ++k) {
    const int idx = (8 * wv + k) * NU + lane;
    const float sg = sigma_[idx];
    const float m  = mu_[idx];
    const float ww = softplus_f(w_[idx]);
    const float ev = erev_[idx];
    ra[k]  = -L2E * sg;
    rc[k]  =  L2E * sg * m;
    rwe[k] = ww * ev;
  }

  const float glp   = softplus_f(gleak[lane]);
  const float cmt   = softplus_f(cm[lane]) * 4.0f;
  const float glvl  = glp * vleak[lane];
  const float dbase = cmt + glp + 1e-8f;

  float v = 0.0f;
  const v2f* sp = sens + (size_t)b * NT * NU + lane;
  v2f se = sp[0];

#pragma unroll 1
  for (int t = 0; t < NT; ++t) {
    const v2f se_next = (t + 1 < NT) ? sp[(size_t)(t + 1) * NU] : (v2f){0.f, 0.f};
#pragma unroll
    for (int u = 0; u < 4; ++u) {
      const int i0 = 8 * wv;
      float n0=0.f,n1=0.f,n2=0.f,n3=0.f, d0=0.f,d1=0.f,d2=0.f,d3=0.f;
#pragma unroll
      for (int k = 0; k < 8; k += 4) {
        // recurrent z bounded (|v|~<=1.5): 4-term product <= ~2^104, no clamp
        const float z0 = fmaf(ra[k+0], bcastf(v, i0+k+0), rc[k+0]);
        const float z1 = fmaf(ra[k+1], bcastf(v, i0+k+1), rc[k+1]);
        const float z2 = fmaf(ra[k+2], bcastf(v, i0+k+2), rc[k+2]);
        const float z3 = fmaf(ra[k+3], bcastf(v, i0+k+3), rc[k+3]);
        float s0, s1, s2, s3;
        sig4(z0, z1, z2, z3, s0, s1, s2, s3);
        n0 = fmaf(rwe[k+0], s0, n0);  d0 = fmaf(fabsf(rwe[k+0]), s0, d0);
        n1 = fmaf(rwe[k+1], s1, n1);  d1 = fmaf(fabsf(rwe[k+1]), s1, d1);
        n2 = fmaf(rwe[k+2], s2, n2);  d2 = fmaf(fabsf(rwe[k+2]), s2, d2);
        n3 = fmaf(rwe[k+3], s3, n3);  d3 = fmaf(fabsf(rwe[k+3]), s3, d3);
      }
      xbuf[u][wv][lane] = (v2f){(n0 + n1) + (n2 + n3), (d0 + d1) + (d2 + d3)};
      __syncthreads();
      v2f tot = xbuf[u][0][lane];
#pragma unroll
      for (int p = 1; p < 8; ++p) tot += xbuf[u][p][lane];
      const float num = fmaf(cmt, v, glvl) + tot.x + se.x;
      const float den = dbase + tot.y + se.y;
      v = num * __builtin_amdgcn_rcpf(den);
      // next write to xbuf[u] is 4 barriers away -> no WAR hazard
    }
    se = se_next;
  }

  if (wv == 0) {
    const float h    = fmaf(v, output_w[lane], output_b[lane]);
    const float mean = wsum64(h) * (1.0f / 64.0f);
    const float d    = h - mean;
    const float var  = wsum64(d * d) * (1.0f / 64.0f);
    const float hn   = d * rsqrtf(var + 1e-5f) * ln_w[lane] + ln_b[lane];
#pragma unroll
    for (int o = 0; o < NO; ++o) {
      const float p = wsum64(hn * fc_w[o * NU + lane]);
      if (lane == 0) out[b * NO + o] = p + fc_b[o];
    }
  }
}

// ---------------- Fallback: round-1 fused kernel (proven 2.17 ms) ----------------
__global__ __launch_bounds__(256, 2) void ltc_fused(
    const float* __restrict__ x,
    const float* __restrict__ input_w, const float* __restrict__ input_b,
    const float* __restrict__ sensory_w, const float* __restrict__ sensory_mu,
    const float* __restrict__ sensory_sigma, const float* __restrict__ sensory_erev,
    const float* __restrict__ w_, const float* __restrict__ mu_,
    const float* __restrict__ sigma_, const float* __restrict__ erev_,
    const float* __restrict__ gleak, const float* __restrict__ vleak,
    const float* __restrict__ cm,
    const float* __restrict__ output_w, const float* __restrict__ output_b,
    const float* __restrict__ ln_w, const float* __restrict__ ln_b,
    const float* __restrict__ fc_w, const float* __restrict__ fc_b,
    float* __restrict__ out)
{
  const int b = blockIdx.x, tid = threadIdx.x, wv = tid >> 6, lane = tid & 63;
  __shared__ float2 xbuf[4][4][NU];
  float sa[32], sc[32], swe[32], swp[32];
#pragma unroll
  for (int k = 0; k < 32; ++k) {
    const int idx = (32 * wv + k) * NU + lane;
    const float ss = sensory_sigma[idx], sm = sensory_mu[idx];
    const float sw = softplus_f(sensory_w[idx]), se = sensory_erev[idx];
    sa[k] = -L2E * ss; sc[k] = L2E * ss * sm; swe[k] = sw * se; swp[k] = sw;
  }
  float ra[16], rc[16], rwe[16], rwp[16];
#pragma unroll
  for (int k = 0; k < 16; ++k) {
    const int idx = (16 * wv + k) * NU + lane;
    const float sg = sigma_[idx], m = mu_[idx];
    const float ww = softplus_f(w_[idx]), ev = erev_[idx];
    ra[k] = -L2E * sg; rc[k] = L2E * sg * m; rwe[k] = ww * ev; rwp[k] = ww;
  }
  const float glp = softplus_f(gleak[lane]);
  const float cmt = softplus_f(cm[lane]) * 4.0f;
  const float glvl = glp * vleak[lane];
  const float dbase = cmt + glp;
  const int ii = 32 * wv + (lane & 31);
  const float iw = input_w[ii], ib = input_b[ii];
  float v = 0.0f;
  const float* xp = x + (size_t)b * NT * NI + ii;
  float xv = xp[0];
#pragma unroll 1
  for (int t = 0; t < NT; ++t) {
    const int tn = (t + 1 < NT) ? (t + 1) : t;
    const float xv_next = xp[(size_t)tn * NI];
    const float inp = fmaf(xv, iw, ib);
    float ns0=0.f,ns1=0.f,ns2=0.f,ns3=0.f, ds0=0.f,ds1=0.f,ds2=0.f,ds3=0.f;
#pragma unroll
    for (int k = 0; k < 32; k += 4) {
      { float z = fmaf(sa[k+0], bcastf(inp,k+0), sc[k+0]);
        float s = __builtin_amdgcn_rcpf(1.0f + __builtin_amdgcn_exp2f(z));
        ns0 = fmaf(swe[k+0], s, ns0); ds0 = fmaf(swp[k+0], s, ds0); }
      { float z = fmaf(sa[k+1], bcastf(inp,k+1), sc[k+1]);
        float s = __builtin_amdgcn_rcpf(1.0f + __builtin_amdgcn_exp2f(z));
        ns1 = fmaf(swe[k+1], s, ns1); ds1 = fmaf(swp[k+1], s, ds1); }
      { float z = fmaf(sa[k+2], bcastf(inp,k+2), sc[k+2]);
        float s = __builtin_amdgcn_rcpf(1.0f + __builtin_amdgcn_exp2f(z));
        ns2 = fmaf(swe[k+2], s, ns2); ds2 = fmaf(swp[k+2], s, ds2); }
      { float z = fmaf(sa[k+3], bcastf(inp,k+3), sc[k+3]);
        float s = __builtin_amdgcn_rcpf(1.0f + __builtin_amdgcn_exp2f(z));
        ns3 = fmaf(swe[k+3], s, ns3); ds3 = fmaf(swp[k+3], s, ds3); }
    }
    const float wns = (ns0+ns1)+(ns2+ns3), wds = (ds0+ds1)+(ds2+ds3);
#pragma unroll
    for (int u = 0; u < 4; ++u) {
      float rn0=0.f,rn1=0.f,rn2=0.f,rn3=0.f, rd0=0.f,rd1=0.f,rd2=0.f,rd3=0.f;
      const int i0 = 16 * wv;
#pragma unroll
      for (int k = 0; k < 16; k += 4) {
        { float z = fmaf(ra[k+0], bcastf(v,i0+k+0), rc[k+0]);
          float s = __builtin_amdgcn_rcpf(1.0f + __builtin_amdgcn_exp2f(z));
          rn0 = fmaf(rwe[k+0], s, rn0); rd0 = fmaf(rwp[k+0], s, rd0); }
        { float z = fmaf(ra[k+1], bcastf(v,i0+k+1), rc[k+1]);
          float s = __builtin_amdgcn_rcpf(1.0f + __builtin_amdgcn_exp2f(z));
          rn1 = fmaf(rwe[k+1], s, rn1); rd1 = fmaf(rwp[k+1], s, rd1); }
        { float z = fmaf(ra[k+2], bcastf(v,i0+k+2), rc[k+2]);
          float s = __builtin_amdgcn_rcpf(1.0f + __builtin_amdgcn_exp2f(z));
          rn2 = fmaf(rwe[k+2], s, rn2); rd2 = fmaf(rwp[k+2], s, rd2); }
        { float z = fmaf(ra[k+3], bcastf(v,i0+k+3), rc[k+3]);
          float s = __builtin_amdgcn_rcpf(1.0f + __builtin_amdgcn_exp2f(z));
          rn3 = fmaf(rwe[k+3], s, rn3); rd3 = fmaf(rwp[k+3], s, rd3); }
      }
      const float np = ((rn0+rn1)+(rn2+rn3)) + wns;
      const float dp = ((rd0+rd1)+(rd2+rd3)) + wds;
      xbuf[u][wv][lane] = make_float2(np, dp);
      __syncthreads();
      const float2 p0 = xbuf[u][0][lane], p1 = xbuf[u][1][lane];
      const float2 p2 = xbuf[u][2][lane], p3 = xbuf[u][3][lane];
      const float num = fmaf(cmt, v, glvl) + ((p0.x+p1.x)+(p2.x+p3.x));
      const float den = dbase + ((p0.y+p1.y)+(p2.y+p3.y)) + 1e-8f;
      v = num * __builtin_amdgcn_rcpf(den);
    }
    xv = xv_next;
  }
  if (wv == 0) {
    const float h = fmaf(v, output_w[lane], output_b[lane]);
    const float mean = wsum64(h) * (1.0f / 64.0f);
    const float d = h - mean;
    const float var = wsum64(d * d) * (1.0f / 64.0f);
    const float hn = d * rsqrtf(var + 1e-5f) * ln_w[lane] + ln_b[lane];
#pragma unroll
    for (int o = 0; o < NO; ++o) {
      const float p = wsum64(hn * fc_w[o * NU + lane]);
      if (lane == 0) out[b * NO + o] = p + fc_b[o];
    }
  }
}

extern "C" void kernel_launch(void* const* d_in, const int* in_sizes, int n_in,
                              void* d_out, int out_size, void* d_ws, size_t ws_size,
                              hipStream_t stream) {
  const float* x             = (const float*)d_in[0];
  const float* input_w       = (const float*)d_in[1];
  const float* input_b       = (const float*)d_in[2];
  const float* sensory_w     = (const float*)d_in[3];
  const float* sensory_mu    = (const float*)d_in[4];
  const float* sensory_sigma = (const float*)d_in[5];
  const float* sensory_erev  = (const float*)d_in[6];
  const float* w_            = (const float*)d_in[7];
  const float* mu_           = (const float*)d_in[8];
  const float* sigma_        = (const float*)d_in[9];
  const float* erev_         = (const float*)d_in[10];
  const float* gleak         = (const float*)d_in[11];
  const float* vleak         = (const float*)d_in[12];
  const float* cm            = (const float*)d_in[13];
  const float* output_w      = (const float*)d_in[14];
  const float* output_b      = (const float*)d_in[15];
  const float* ln_w          = (const float*)d_in[16];
  const float* ln_b          = (const float*)d_in[17];
  const float* fc_w          = (const float*)d_in[18];
  const float* fc_b          = (const float*)d_in[19];
  float* out = (float*)d_out;

  const size_t need = (size_t)NB * NT * NU * 2 * sizeof(float);  // 134 MB
  if (ws_size >= need) {
    v2f* sens = (v2f*)d_ws;
    ltc_sensory<<<dim3(NB, NT / 8), dim3(512), 0, stream>>>(
        x, input_w, input_b, sensory_w, sensory_mu, sensory_sigma, sensory_erev,
        sens);
    ltc_scan<<<dim3(NB), dim3(512), 0, stream>>>(
        sens, w_, mu_, sigma_, erev_, gleak, vleak, cm,
        output_w, output_b, ln_w, ln_b, fc_w, fc_b, out);
  } else {
    ltc_fused<<<dim3(NB), dim3(256), 0, stream>>>(
        x, input_w, input_b, sensory_w, sensory_mu, sensory_sigma, sensory_erev,
        w_, mu_, sigma_, erev_, gleak, vleak, cm, output_w, output_b,
        ln_w, ln_b, fc_w, fc_b, out);
  }
}

// Round 6
// 2574.855 us; speedup vs baseline: 1.2212x; 1.2212x over previous
//
#include <hip/hip_runtime.h>
#include <hip/hip_bf16.h>

// LTC fused scan, round 6 (= round 5 + sensory-reduction fix).
// One kernel. B=512 rows, one 512-thread workgroup (8 waves) per row.
// lane = unit j (U=64). Wave w owns sensory i in [16w,16w+16),
// recurrent i in [8w,8w+8).
//
// Per-term math: sigmoid s = 1/(1+exp2(a*v+c)), a=-log2e*sigma,
// c=log2e*sigma*mu; num-weight swe=softplus(w)*erev, den-weight |swe| via
// the FREE fma abs() modifier (erev=+-1). 3 param floats/term.
// sig4: ONE v_rcp per 4 sigmoids via product tree (exact).
// 4 independent accumulator chains (round-3 lesson: single chain serializes).
// Software pipeline (round-4 lesson): fill each unfold's barrier/LDS-read
// latency window with one t+1 sensory sig4-batch (v-independent).
//
// ROUND-5 BUG FIX: the per-wave sensory partial (wns,wds) must go INTO the
// xbuf[u] write so the cross-wave LDS reduce sums sensory over ALL 8 waves
// (round 5 added only the local wave's partial after the reduce -> each
// wave's v missed 7/8 of the sensory term, absmax 1.71).

#define NB 512
#define NT 512
#define NI 128
#define NU 64
#define NO 15
#define L2E 1.44269504088896340736f

typedef float v2f __attribute__((ext_vector_type(2)));

__device__ __forceinline__ float bcastf(float v, int lane) {
  return __int_as_float(__builtin_amdgcn_readlane(__float_as_int(v), lane));
}

__device__ __forceinline__ float wsum64(float x) {
#pragma unroll
  for (int m = 32; m >= 1; m >>= 1) x += __shfl_xor(x, m, 64);
  return x;
}

__device__ __forceinline__ float softplus_f(float x) {
  return log1pf(expf(x));
}

// 4 sigmoids s_i = 1/(1+exp2(z_i)) with ONE v_rcp via product tree (exact).
__device__ __forceinline__ void sig4(float z0, float z1, float z2, float z3,
                                     float& s0, float& s1, float& s2, float& s3) {
  const float e0 = __builtin_amdgcn_exp2f(z0);
  const float e1 = __builtin_amdgcn_exp2f(z1);
  const float e2 = __builtin_amdgcn_exp2f(z2);
  const float e3 = __builtin_amdgcn_exp2f(z3);
  const float A = 1.0f + e0, B = 1.0f + e1, C = 1.0f + e2, D = 1.0f + e3;
  const float pAB = A * B, pCD = C * D;
  const float r = __builtin_amdgcn_rcpf(pAB * pCD);
  const float rAB = r * pCD, rCD = r * pAB;
  s0 = rAB * B; s1 = rAB * A; s2 = rCD * D; s3 = rCD * C;
}

// One sensory batch of 4 terms (k..k+3); clamp +-30 keeps the 4-term
// product finite (|z| can reach ~70). k is a compile-time constant.
#define SENS_BATCH(k, inp, na, nb, da, db)                                     \
  {                                                                            \
    const float z0 = fminf(fmaxf(fmaf(sa[(k)+0], bcastf((inp), (k)+0), sc[(k)+0]), -30.f), 30.f); \
    const float z1 = fminf(fmaxf(fmaf(sa[(k)+1], bcastf((inp), (k)+1), sc[(k)+1]), -30.f), 30.f); \
    const float z2 = fminf(fmaxf(fmaf(sa[(k)+2], bcastf((inp), (k)+2), sc[(k)+2]), -30.f), 30.f); \
    const float z3 = fminf(fmaxf(fmaf(sa[(k)+3], bcastf((inp), (k)+3), sc[(k)+3]), -30.f), 30.f); \
    float s0, s1, s2, s3;                                                      \
    sig4(z0, z1, z2, z3, s0, s1, s2, s3);                                      \
    na = fmaf(swe[(k)+0], s0, na);  da = fmaf(fabsf(swe[(k)+0]), s0, da);      \
    nb = fmaf(swe[(k)+1], s1, nb);  db = fmaf(fabsf(swe[(k)+1]), s1, db);      \
    na = fmaf(swe[(k)+2], s2, na);  da = fmaf(fabsf(swe[(k)+2]), s2, da);      \
    nb = fmaf(swe[(k)+3], s3, nb);  db = fmaf(fabsf(swe[(k)+3]), s3, db);      \
  }

__global__ __launch_bounds__(512, 2) void ltc_fused(
    const float* __restrict__ x,
    const float* __restrict__ input_w, const float* __restrict__ input_b,
    const float* __restrict__ sensory_w, const float* __restrict__ sensory_mu,
    const float* __restrict__ sensory_sigma, const float* __restrict__ sensory_erev,
    const float* __restrict__ w_, const float* __restrict__ mu_,
    const float* __restrict__ sigma_, const float* __restrict__ erev_,
    const float* __restrict__ gleak, const float* __restrict__ vleak,
    const float* __restrict__ cm,
    const float* __restrict__ output_w, const float* __restrict__ output_b,
    const float* __restrict__ ln_w, const float* __restrict__ ln_b,
    const float* __restrict__ fc_w, const float* __restrict__ fc_b,
    float* __restrict__ out)
{
  const int b    = blockIdx.x;
  const int tid  = threadIdx.x;
  const int wv   = tid >> 6;            // 0..7
  const int lane = tid & 63;            // unit j

  __shared__ v2f xbuf[4][8][NU];        // [unfold][wave][lane] (num,den) partial

  // ---- sensory params: i = 16*wv + k, j = lane (48 regs) ----
  float sa[16], sc[16], swe[16];
#pragma unroll
  for (int k = 0; k < 16; ++k) {
    const int idx = (16 * wv + k) * NU + lane;
    const float ss = sensory_sigma[idx];
    const float sm = sensory_mu[idx];
    const float sw = softplus_f(sensory_w[idx]);
    const float ev = sensory_erev[idx];
    sa[k]  = -L2E * ss;
    sc[k]  =  L2E * ss * sm;
    swe[k] = sw * ev;                   // |swe| = softplus(w) since |erev|=1
  }
  // ---- recurrent params: i = 8*wv + k, j = lane (24 regs) ----
  float ra[8], rc[8], rwe[8];
#pragma unroll
  for (int k = 0; k < 8; ++k) {
    const int idx = (8 * wv + k) * NU + lane;
    const float sg = sigma_[idx];
    const float m  = mu_[idx];
    const float ww = softplus_f(w_[idx]);
    const float ev = erev_[idx];
    ra[k]  = -L2E * sg;
    rc[k]  =  L2E * sg * m;
    rwe[k] = ww * ev;
  }

  // ---- per-neuron constants (lane = j) ----
  const float glp   = softplus_f(gleak[lane]);
  const float cmt   = softplus_f(cm[lane]) * 4.0f;   // softplus(cm)/(1/UNFOLDS)
  const float glvl  = glp * vleak[lane];
  const float dbase = cmt + glp + 1e-8f;

  // lane's sensory x index (lanes 16..63 duplicate 0..15)
  const int ii = 16 * wv + (lane & 15);
  const float iw = input_w[ii];
  const float ib = input_b[ii];
  const float* xp = x + (size_t)b * NT * NI + ii;

  float v = 0.0f;

  // ---- prologue: this wave's sensory partial for t=0 ----
  float wns, wds;
  {
    const float inp0 = fmaf(xp[0], iw, ib);
    float na = 0.f, nb = 0.f, da = 0.f, db = 0.f;
    SENS_BATCH(0,  inp0, na, nb, da, db);
    SENS_BATCH(4,  inp0, na, nb, da, db);
    SENS_BATCH(8,  inp0, na, nb, da, db);
    SENS_BATCH(12, inp0, na, nb, da, db);
    wns = na + nb;  wds = da + db;
  }
  float xv_next = xp[1 * NI];           // x at t=1

#pragma unroll 1
  for (int t = 0; t < NT; ++t) {
    // prefetch x for t+2 (clamped; tail iterations compute unused sums)
    const int t2 = (t + 2 < NT) ? (t + 2) : (NT - 1);
    const float xv2 = xp[(size_t)t2 * NI];
    const float inp_nx = fmaf(xv_next, iw, ib);   // input for t+1

    // next-t sensory accumulators (filled one batch per unfold)
    float na = 0.f, nb = 0.f, da = 0.f, db = 0.f;

    const int i0 = 8 * wv;
#pragma unroll
    for (int u = 0; u < 4; ++u) {
      // ---- recurrent: 8 terms, 2 sig4 batches, 4 chains ----
      float n0=0.f,n1=0.f,n2=0.f,n3=0.f, d0=0.f,d1=0.f,d2=0.f,d3=0.f;
#pragma unroll
      for (int k = 0; k < 8; k += 4) {
        // recurrent z bounded (|v|<~1.5): 4-term product <= ~2^104, no clamp
        const float z0 = fmaf(ra[k+0], bcastf(v, i0+k+0), rc[k+0]);
        const float z1 = fmaf(ra[k+1], bcastf(v, i0+k+1), rc[k+1]);
        const float z2 = fmaf(ra[k+2], bcastf(v, i0+k+2), rc[k+2]);
        const float z3 = fmaf(ra[k+3], bcastf(v, i0+k+3), rc[k+3]);
        float s0, s1, s2, s3;
        sig4(z0, z1, z2, z3, s0, s1, s2, s3);
        n0 = fmaf(rwe[k+0], s0, n0);  d0 = fmaf(fabsf(rwe[k+0]), s0, d0);
        n1 = fmaf(rwe[k+1], s1, n1);  d1 = fmaf(fabsf(rwe[k+1]), s1, d1);
        n2 = fmaf(rwe[k+2], s2, n2);  d2 = fmaf(fabsf(rwe[k+2]), s2, d2);
        n3 = fmaf(rwe[k+3], s3, n3);  d3 = fmaf(fabsf(rwe[k+3]), s3, d3);
      }
      // FIX: include this wave's CURRENT-t sensory partial in the LDS
      // partial so the cross-wave reduce sums sensory over all 8 waves.
      xbuf[u][wv][lane] = (v2f){((n0 + n1) + (n2 + n3)) + wns,
                                ((d0 + d1) + (d2 + d3)) + wds};
      __syncthreads();

      // issue the 8 partial reads FIRST...
      const v2f p0 = xbuf[u][0][lane];
      const v2f p1 = xbuf[u][1][lane];
      const v2f p2 = xbuf[u][2][lane];
      const v2f p3 = xbuf[u][3][lane];
      const v2f p4 = xbuf[u][4][lane];
      const v2f p5 = xbuf[u][5][lane];
      const v2f p6 = xbuf[u][6][lane];
      const v2f p7 = xbuf[u][7][lane];

      // ...fill the latency window with one t+1 sensory batch (v-independent)
      if (u == 0)      SENS_BATCH(0,  inp_nx, na, nb, da, db)
      else if (u == 1) SENS_BATCH(4,  inp_nx, na, nb, da, db)
      else if (u == 2) SENS_BATCH(8,  inp_nx, na, nb, da, db)
      else             SENS_BATCH(12, inp_nx, na, nb, da, db)

      // ...then consume the partials (full recurrent + full sensory)
      const v2f tot = (((p0 + p1) + (p2 + p3)) + ((p4 + p5) + (p6 + p7)));
      const float num = fmaf(cmt, v, glvl) + tot.x;
      const float den = dbase + tot.y;
      v = num * __builtin_amdgcn_rcpf(den);
      // next write to xbuf[u] is 3+ barriers away -> no WAR hazard
    }

    // roll the pipeline
    wns = na + nb;
    wds = da + db;
    xv_next = xv2;
  }

  // ---- head: affine out-map, LayerNorm(eps=1e-5), fc (O=15) ----
  if (wv == 0) {
    const float h    = fmaf(v, output_w[lane], output_b[lane]);
    const float mean = wsum64(h) * (1.0f / 64.0f);
    const float d    = h - mean;
    const float var  = wsum64(d * d) * (1.0f / 64.0f);
    const float hn   = d * rsqrtf(var + 1e-5f) * ln_w[lane] + ln_b[lane];
#pragma unroll
    for (int o = 0; o < NO; ++o) {
      const float p = wsum64(hn * fc_w[o * NU + lane]);
      if (lane == 0) out[b * NO + o] = p + fc_b[o];
    }
  }
}

extern "C" void kernel_launch(void* const* d_in, const int* in_sizes, int n_in,
                              void* d_out, int out_size, void* d_ws, size_t ws_size,
                              hipStream_t stream) {
  const float* x             = (const float*)d_in[0];
  const float* input_w       = (const float*)d_in[1];
  const float* input_b       = (const float*)d_in[2];
  const float* sensory_w     = (const float*)d_in[3];
  const float* sensory_mu    = (const float*)d_in[4];
  const float* sensory_sigma = (const float*)d_in[5];
  const float* sensory_erev  = (const float*)d_in[6];
  const float* w_            = (const float*)d_in[7];
  const float* mu_           = (const float*)d_in[8];
  const float* sigma_        = (const float*)d_in[9];
  const float* erev_         = (const float*)d_in[10];
  const float* gleak         = (const float*)d_in[11];
  const float* vleak         = (const float*)d_in[12];
  const float* cm            = (const float*)d_in[13];
  const float* output_w      = (const float*)d_in[14];
  const float* output_b      = (const float*)d_in[15];
  const float* ln_w          = (const float*)d_in[16];
  const float* ln_b          = (const float*)d_in[17];
  const float* fc_w          = (const float*)d_in[18];
  const float* fc_b          = (const float*)d_in[19];
  float* out = (float*)d_out;

  ltc_fused<<<dim3(NB), dim3(512), 0, stream>>>(
      x, input_w, input_b, sensory_w, sensory_mu, sensory_sigma, sensory_erev,
      w_, mu_, sigma_, erev_, gleak, vleak, cm, output_w, output_b,
      ln_w, ln_b, fc_w, fc_b, out);
}